// Round 11
// baseline (793.468 us; speedup 1.0000x reference)
//
#include <hip/hip_runtime.h>

typedef unsigned short u16;
typedef unsigned int u32;
typedef unsigned long long u64;
typedef __bf16 bf16x8 __attribute__((ext_vector_type(8)));
typedef float v4f32 __attribute__((ext_vector_type(4)));
typedef float f32x2 __attribute__((ext_vector_type(2)));

#define NP 8192
#define NM 512
#define LTOT 131072
#define NBM 4096
#define R2F 0.009999999776482582f   // float(0.1*0.1)

__device__ __forceinline__ float bf2f(u16 u) { return __uint_as_float(((u32)u) << 16); }
__device__ __forceinline__ u16 f2bf(float f) {
  u32 u = __float_as_uint(f);
  return (u16)((u + 0x7fffu + ((u >> 16) & 1u)) >> 16);
}
__device__ __forceinline__ void gl16(const void* g, void* l) {
  __builtin_amdgcn_global_load_lds((const __attribute__((address_space(1))) u32*)g,
                                   (__attribute__((address_space(3))) u32*)l, 16, 0, 0);
}

// packed fp32 (VOP3P): identical RN rounding to scalar v_add_f32/v_mul_f32.
// Bit-exactness of pk distances validated in R4-R6 benches (absmax unchanged).
__device__ __forceinline__ f32x2 pk_add(f32x2 a, f32x2 b) {
  f32x2 r; asm("v_pk_add_f32 %0, %1, %2" : "=v"(r) : "v"(a), "v"(b)); return r;
}
__device__ __forceinline__ f32x2 pk_mul(f32x2 a, f32x2 b) {
  f32x2 r; asm("v_pk_mul_f32 %0, %1, %2" : "=v"(r) : "v"(a), "v"(b)); return r;
}

// wave64 max of u64 keys via DPP ladder; lane 63 ends with the full max.
__device__ __forceinline__ u64 wave_max64_dpp(u64 k) {
#define DPP_STEP(CTRL) { \
    u32 lo_ = (u32)__builtin_amdgcn_update_dpp(0, (int)(u32)k, CTRL, 0xF, 0xF, true); \
    u32 hi_ = (u32)__builtin_amdgcn_update_dpp(0, (int)(u32)(k >> 32), CTRL, 0xF, 0xF, true); \
    u64 o_ = ((u64)hi_ << 32) | lo_; \
    if (o_ > k) k = o_; }
  DPP_STEP(0x111)  // row_shr:1
  DPP_STEP(0x112)  // row_shr:2
  DPP_STEP(0x114)  // row_shr:4
  DPP_STEP(0x118)  // row_shr:8
  DPP_STEP(0x142)  // row_bcast:15
  DPP_STEP(0x143)  // row_bcast:31
#undef DPP_STEP
  return k;
}

#define MFMA_COMPUTE_P(ASP, BSP) do { \
  bf16x8 a_[4], b_[4]; \
  _Pragma("unroll") \
  for (int mi_ = 0; mi_ < 4; ++mi_) a_[mi_] = *(const bf16x8*)&(ASP)[(wrow + mi_*16 + l15)*32 + l4*8]; \
  _Pragma("unroll") \
  for (int ni_ = 0; ni_ < 4; ++ni_) b_[ni_] = *(const bf16x8*)&(BSP)[(wcol + ni_*16 + l15)*32 + l4*8]; \
  _Pragma("unroll") \
  for (int mi_ = 0; mi_ < 4; ++mi_) { \
    _Pragma("unroll") \
    for (int ni_ = 0; ni_ < 4; ++ni_) \
      acc[mi_][ni_] = __builtin_amdgcn_mfma_f32_16x16x32_bf16(a_[mi_], b_[ni_], acc[mi_][ni_], 0, 0, 0); \
  } \
} while (0)

// ---------------- FPS (blocks 0..7) + prep work (blocks 8..215) ----------------
// R10 body with ONLY the distance loop pk-ified (64 VALU vs 144 per wave/step).
// Reduce (tree-max + bit-exact scan + u64 DPP + rotating-slot atomic) unchanged.
__global__ __launch_bounds__(512) void k_fps_prep(
    const float* __restrict__ p, const float* __restrict__ x,
    const float* __restrict__ W1, const float* __restrict__ W2, const float* __restrict__ W3,
    float* __restrict__ outP, float* __restrict__ outC, float* __restrict__ outX,
    u16* __restrict__ w1b, u16* __restrict__ w2b, u16* __restrict__ w3b,
    float* __restrict__ statz, int* __restrict__ idxb)
{
  const int tid = threadIdx.x;
  if (blockIdx.x >= 8) {
    for (size_t i = (size_t)(blockIdx.x - 8) * 512 + tid; i < 855040; i += 208 * 512) {
      if (i < 196608)      outP[i] = p[i];
      else if (i < 393216) outX[i - 196608] = x[i - 196608];
      else if (i < 458752) w1b[i - 393216] = f2bf(W1[i - 393216]);
      else if (i < 720896) w2b[i - 458752] = f2bf(W2[i - 458752]);
      else if (i < 851968) w3b[i - 720896] = f2bf(W3[i - 720896]);
      else                 statz[i - 851968] = 0.0f;
    }
    return;
  }
  const int b = blockIdx.x;
  const float* pb = p + (size_t)b * NP * 3;
  __shared__ float pl[NP * 3];
  __shared__ u64 slot[3];
  f32x2 pxv[8], pyv[8], pzv[8];
  float md[16];
  u32 nj[16];
  #pragma unroll
  for (int q = 0; q < 16; ++q) {
    int j = tid + (q << 9);
    float a0 = pb[j*3+0], a1 = pb[j*3+1], a2 = pb[j*3+2];
    pxv[q>>1][q&1] = a0; pyv[q>>1][q&1] = a1; pzv[q>>1][q&1] = a2; md[q] = 1e10f;
    nj[q] = ~(u32)j;
    pl[j*3+0] = a0; pl[j*3+1] = a1; pl[j*3+2] = a2;
  }
  if (tid < 3) slot[tid] = 0ull;
  __syncthreads();
  int last = 0;
  float* ctr = outC + (size_t)b * NM * 3;
  int* ip = idxb + b * NM;
  for (int s = 0; s < NM; ++s) {
    const int sl = s % 3;
    float lx = pl[last*3], ly = pl[last*3+1], lz = pl[last*3+2];
    if (tid == 0) {
      ip[s] = last; ctr[s*3] = lx; ctr[s*3+1] = ly; ctr[s*3+2] = lz;
      slot[(s+1) % 3] = 0ull;   // safe: its readers finished 2 barriers ago
    }
    // packed-f32 min_d update: a + (-b) == a - b bit-exactly; pk rounding == scalar RN
    const f32x2 nlx = {-lx, -lx}, nly = {-ly, -ly}, nlz = {-lz, -lz};
    #pragma unroll
    for (int h = 0; h < 8; ++h) {
      f32x2 dx = pk_add(pxv[h], nlx);
      f32x2 dy = pk_add(pyv[h], nly);
      f32x2 dz = pk_add(pzv[h], nlz);
      f32x2 d2 = pk_add(pk_add(pk_mul(dx,dx), pk_mul(dy,dy)), pk_mul(dz,dz));
      md[2*h]   = fminf(md[2*h],   d2.x);
      md[2*h+1] = fminf(md[2*h+1], d2.y);
    }
    // thread-local tree max (exact; order-independent, no NaN/-0)
    float t0 = fmaxf(fmaxf(md[0], md[1]),  fmaxf(md[2], md[3]));
    float t1 = fmaxf(fmaxf(md[4], md[5]),  fmaxf(md[6], md[7]));
    float t2 = fmaxf(fmaxf(md[8], md[9]),  fmaxf(md[10], md[11]));
    float t3 = fmaxf(fmaxf(md[12], md[13]), fmaxf(md[14], md[15]));
    float tmax = fmaxf(fmaxf(t0, t1), fmaxf(t2, t3));
    u32 tb = __float_as_uint(tmax);
    // smallest local j attaining tmax (bit-exact match; umax of ~j == umin of j)
    u32 cand = 0;
    #pragma unroll
    for (int q = 0; q < 16; ++q) {
      u32 c = (__float_as_uint(md[q]) == tb) ? nj[q] : 0u;
      cand = c > cand ? c : cand;
    }
    u64 key = wave_max64_dpp(((u64)tb << 32) | (u64)cand);
    u32 klo = (u32)__builtin_amdgcn_readlane((int)(u32)key, 63);
    u32 khi = (u32)__builtin_amdgcn_readlane((int)(u32)(key >> 32), 63);
    if ((tid & 63) == 0)
      __hip_atomic_fetch_max(&slot[sl], ((u64)khi << 32) | klo,
                             __ATOMIC_RELAXED, __HIP_MEMORY_SCOPE_WORKGROUP);
    __syncthreads();
    last = (int)(~(u32)(slot[sl] & 0xffffffffull));
  }
}

// ---------------- ball query + gather: one wave per center ----------------
__global__ __launch_bounds__(256) void k_group(
    const float* __restrict__ p, const float* __restrict__ x,
    const float* __restrict__ ctr, const int* __restrict__ idxb,
    u16* __restrict__ f0)
{
  const int tid = threadIdx.x, wv = tid >> 6, lane = tid & 63;
  const int cm = blockIdx.x * 4 + wv;
  const int b = cm >> 9;
  __shared__ int selS[4][33];
  volatile int* sel = selS[wv];
  const float cx0 = ctr[cm*3+0], cy0 = ctr[cm*3+1], cz0 = ctr[cm*3+2];
  const float* pb = p + (size_t)b * NP * 3;
  int cnt = 0;
  for (int ch = 0; ch < NP/64; ++ch) {
    if (cnt >= 32) break;
    int j = (ch << 6) + lane;
    float qx = pb[j*3], qy = pb[j*3+1], qz = pb[j*3+2];
    float dx = __fsub_rn(cx0,qx), dy = __fsub_rn(cy0,qy), dz = __fsub_rn(cz0,qz);
    float d2 = __fadd_rn(__fadd_rn(__fmul_rn(dx,dx),__fmul_rn(dy,dy)),__fmul_rn(dz,dz));
    bool pr = d2 < R2F;
    u64 msk = __ballot(pr);
    int pos = cnt + (int)__popcll(msk & ((1ull << lane) - 1ull));
    if (pr && pos < 32) sel[pos] = j;
    cnt += (int)__popcll(msk);
  }
  if (lane < 32) {
    int jj = (lane < cnt) ? sel[lane] : sel[0];
    const float* xb = x + (size_t)b * 3 * NP;
    int ic = idxb[cm];
    float gx = pb[jj*3], gy = pb[jj*3+1], gz = pb[jj*3+2];
    size_t col = (size_t)cm * 32 + lane;
    f0[0*(size_t)LTOT + col] = f2bf(gx - cx0);
    f0[1*(size_t)LTOT + col] = f2bf(gy - cy0);
    f0[2*(size_t)LTOT + col] = f2bf(gz - cz0);
    f0[3*(size_t)LTOT + col] = f2bf(xb[jj]      - xb[ic]);
    f0[4*(size_t)LTOT + col] = f2bf(xb[NP+jj]   - xb[NP+ic]);
    f0[5*(size_t)LTOT + col] = f2bf(xb[2*NP+jj] - xb[2*NP+ic]);
  }
}

// ---------------- second-moment stats of f0 (6 sums + 21 upper-tri products) ----------------
__global__ __launch_bounds__(256) void k_cov(const u16* __restrict__ f0, float* __restrict__ cov)
{
  const int tid = threadIdx.x;
  const size_t col = (size_t)blockIdx.x * 256 + tid;
  float f[6];
  #pragma unroll
  for (int c = 0; c < 6; ++c) f[c] = bf2f(f0[(size_t)c * LTOT + col]);
  float v[27];
  int n = 0;
  #pragma unroll
  for (int c = 0; c < 6; ++c) v[n++] = f[c];
  #pragma unroll
  for (int i = 0; i < 6; ++i)
    #pragma unroll
    for (int j = i; j < 6; ++j) v[n++] = f[i] * f[j];
  #pragma unroll
  for (int k = 0; k < 27; ++k) {
    float s = v[k];
    #pragma unroll
    for (int off = 1; off < 64; off <<= 1) s += __shfl_xor(s, off);
    v[k] = s;
  }
  __shared__ float ls[27];
  if (tid < 27) ls[tid] = 0.f;
  __syncthreads();
  if ((tid & 63) == 0) {
    #pragma unroll
    for (int k = 0; k < 27; ++k) atomicAdd(&ls[k], v[k]);
  }
  __syncthreads();
  if (tid < 27) atomicAdd(&cov[tid], ls[tid]);
}

// analytic BN params for h1 = W0 @ f0 : mu = W0 m, E2 = w^T (Sff/N) w
__global__ void k_fin1(const float* __restrict__ cov, const float* __restrict__ W0,
                       const float* __restrict__ g, const float* __restrict__ be,
                       float* __restrict__ S, float* __restrict__ T)
{
  int c = threadIdx.x;   // 256 channels
  const float inv = 1.0f / 131072.0f;
  float w[6];
  #pragma unroll
  for (int k = 0; k < 6; ++k) w[k] = W0[c*6 + k];
  float mu = 0.f;
  #pragma unroll
  for (int k = 0; k < 6; ++k) mu = fmaf(w[k], cov[k], mu);
  mu *= inv;
  float e2 = 0.f;
  int n = 6;
  #pragma unroll
  for (int i = 0; i < 6; ++i)
    #pragma unroll
    for (int j = i; j < 6; ++j) {
      float coeff = (i == j) ? w[i]*w[j] : 2.f*w[i]*w[j];
      e2 = fmaf(coeff, cov[n++] * inv, e2);
    }
  float var = e2 - mu * mu;
  float s = g[c] / sqrtf(var + 1e-5f);
  S[c] = s; T[c] = be[c] - mu * s;
}

// ---------------- reduce gemm3's per-block partial stats -> BN params for h3 ----------------
__global__ __launch_bounds__(256) void k_red(
    const float* __restrict__ pS, const float* __restrict__ pQ,
    const float* __restrict__ g, const float* __restrict__ be,
    float* __restrict__ S, float* __restrict__ T)
{
  const int c = blockIdx.x;            // 512 channels
  const int tid = threadIdx.x;
  const int oTc = c >> 7, lc = c & 127;
  float s = 0.f, q = 0.f;
  for (int j = tid; j < 1024; j += 256) {      // 1024 cT blocks with this oT
    size_t idx = (size_t)(j * 4 + oTc) * 128 + lc;
    s += pS[idx]; q += pQ[idx];
  }
  #pragma unroll
  for (int off = 1; off < 64; off <<= 1) { s += __shfl_xor(s, off); q += __shfl_xor(q, off); }
  __shared__ float ls[4], lq[4];
  if ((tid & 63) == 0) { ls[tid >> 6] = s; lq[tid >> 6] = q; }
  __syncthreads();
  if (tid == 0) {
    float ss = ls[0] + ls[1] + ls[2] + ls[3];
    float qq = lq[0] + lq[1] + lq[2] + lq[3];
    const float inv = 1.0f / 131072.0f;
    float mu = ss * inv;
    float var = qq * inv - mu * mu;
    float sc = g[c] / sqrtf(var + 1e-5f);
    S[c] = sc; T[c] = be[c] - mu * sc;
  }
}

// affine+relu transform of an 8-element bf16 chunk, store to LDS
__device__ __forceinline__ void xf_store(u16* Bs, int idx, uint4 q, int cb,
                                         const float* sS, const float* sT)
{
  u32 w[4]; u32 qa[4] = {q.x, q.y, q.z, q.w};
  #pragma unroll
  for (int t2 = 0; t2 < 4; ++t2) {
    float a  = fmaxf(fmaf(sS[cb + 2*t2],     bf2f((u16)(qa[t2] & 0xffffu)), sT[cb + 2*t2]), 0.f);
    float bv = fmaxf(fmaf(sS[cb + 2*t2 + 1], bf2f((u16)(qa[t2] >> 16)),     sT[cb + 2*t2 + 1]), 0.f);
    w[t2] = (u32)f2bf(a) | ((u32)f2bf(bv) << 16);
  }
  *(uint4*)&Bs[idx * 8] = make_uint4(w[0], w[1], w[2], w[3]);
}

// ---------------- GEMM12: fused conv1 — h2 = W1 @ bnrelu(W0@f0) + b1 ; fmax ----------------
__global__ __launch_bounds__(256) void k_gemm12(
    const u16* __restrict__ wA, const u16* __restrict__ f0,
    const float* __restrict__ W0,
    const float* __restrict__ Sc, const float* __restrict__ Tc,
    const float* __restrict__ bias,
    u16* __restrict__ h2, u16* __restrict__ fmaxb)
{
  __shared__ alignas(16) u16 As[4096], As2[4096];
  __shared__ alignas(16) u16 Bs[4096], Bs2[4096];
  __shared__ float w0l[1536];
  __shared__ float sS[256], sT[256];
  const int tid = threadIdx.x;
  sS[tid] = Sc[tid]; sT[tid] = Tc[tid];
  for (int i = tid; i < 1536; i += 256) w0l[i] = W0[i];
  const int oT = blockIdx.x & 1, cT = blockIdx.x >> 1;
  const int lane = tid & 63, wv = tid >> 6;
  const int wrow = (wv >> 1) * 64, wcol = (wv & 1) * 64;
  const int l15 = lane & 15, l4 = lane >> 4;
  const int myc = tid >> 1;                       // 0..127
  const int ch0 = (tid & 1) * 16;                 // 0 or 16
  const size_t gcol = (size_t)cT * 128 + myc;
  float fin[6];
  #pragma unroll
  for (int c = 0; c < 6; ++c) fin[c] = bf2f(f0[(size_t)c * LTOT + gcol]);
  v4f32 acc[4][4];
  #pragma unroll
  for (int mi = 0; mi < 4; ++mi)
    #pragma unroll
    for (int ni = 0; ni < 4; ++ni) acc[mi][ni] = (v4f32){0.f,0.f,0.f,0.f};
  const int idx0 = tid, idx1 = 256 + tid;
  const int r0 = idx0 >> 2, sg0 = idx0 & 3, r1 = idx1 >> 2, sg1 = idx1 & 3;
  __syncthreads();   // w0l, sS/sT visible
  for (int kt = 0; kt < 8; kt += 2) {
    if (kt) __syncthreads();
    gl16(wA + (size_t)(oT*128 + r0) * 256 + kt*32 + sg0*8, &As[idx0 * 8]);
    gl16(wA + (size_t)(oT*128 + r1) * 256 + kt*32 + sg1*8, &As[idx1 * 8]);
    gl16(wA + (size_t)(oT*128 + r0) * 256 + (kt+1)*32 + sg0*8, &As2[idx0 * 8]);
    gl16(wA + (size_t)(oT*128 + r1) * 256 + (kt+1)*32 + sg1*8, &As2[idx1 * 8]);
    #pragma unroll
    for (int half = 0; half < 2; ++half) {
      u16* Bdst = half ? Bs2 : Bs;
      u32 wp[8];
      #pragma unroll
      for (int j = 0; j < 16; j += 2) {
        const int o0 = (kt + half)*32 + ch0 + j;
        float v0 = 0.f, v1 = 0.f;
        #pragma unroll
        for (int c = 0; c < 6; ++c) {
          v0 = fmaf(w0l[o0*6 + c], fin[c], v0);
          v1 = fmaf(w0l[(o0+1)*6 + c], fin[c], v1);
        }
        float h0 = bf2f(f2bf(v0)), h1v = bf2f(f2bf(v1));
        float a0 = fmaxf(fmaf(sS[o0],     h0,  sT[o0]),     0.f);
        float a1 = fmaxf(fmaf(sS[o0 + 1], h1v, sT[o0 + 1]), 0.f);
        wp[j >> 1] = (u32)f2bf(a0) | ((u32)f2bf(a1) << 16);
      }
      *(uint4*)&Bdst[myc*32 + ch0]     = make_uint4(wp[0], wp[1], wp[2], wp[3]);
      *(uint4*)&Bdst[myc*32 + ch0 + 8] = make_uint4(wp[4], wp[5], wp[6], wp[7]);
    }
    asm volatile("s_waitcnt vmcnt(0)" ::: "memory");
    __syncthreads();
    MFMA_COMPUTE_P(As, Bs);
    MFMA_COMPUTE_P(As2, Bs2);
  }
  const int oB = oT*128 + wrow + l4*4;
  const int cB = cT*128 + wcol + l15;
  #pragma unroll
  for (int mi = 0; mi < 4; ++mi) {
    const float4 bv = *(const float4*)&bias[oB + mi*16];
    #pragma unroll
    for (int ni = 0; ni < 4; ++ni) {
      acc[mi][ni][0] += bv.x; acc[mi][ni][1] += bv.y;
      acc[mi][ni][2] += bv.z; acc[mi][ni][3] += bv.w;
    }
  }
  #pragma unroll
  for (int mi = 0; mi < 4; ++mi) {
    const int o = oB + mi*16;
    const size_t rb = (size_t)(o >> 5) * LTOT * 32 + (o & 31);
    #pragma unroll
    for (int ni = 0; ni < 4; ++ni) {
      ushort4 u; u.x = f2bf(acc[mi][ni][0]); u.y = f2bf(acc[mi][ni][1]);
      u.z = f2bf(acc[mi][ni][2]); u.w = f2bf(acc[mi][ni][3]);
      *(ushort4*)&h2[rb + (size_t)(cB + ni*16) * 32] = u;
    }
  }
  #pragma unroll
  for (int g = 0; g < 2; ++g) {
    const int bm = (cT*128 + wcol + g*32) >> 5;
    #pragma unroll
    for (int mi = 0; mi < 4; ++mi) {
      float a0 = fmaxf(acc[mi][2*g][0], acc[mi][2*g+1][0]);
      float a1 = fmaxf(acc[mi][2*g][1], acc[mi][2*g+1][1]);
      float a2 = fmaxf(acc[mi][2*g][2], acc[mi][2*g+1][2]);
      float a3 = fmaxf(acc[mi][2*g][3], acc[mi][2*g+1][3]);
      #pragma unroll
      for (int off = 1; off < 16; off <<= 1) {
        a0 = fmaxf(a0, __shfl_xor(a0, off));
        a1 = fmaxf(a1, __shfl_xor(a1, off));
        a2 = fmaxf(a2, __shfl_xor(a2, off));
        a3 = fmaxf(a3, __shfl_xor(a3, off));
      }
      if (l15 == 0) {
        const int o = oB + mi*16;
        ushort4 u; u.x=f2bf(a0); u.y=f2bf(a1); u.z=f2bf(a2); u.w=f2bf(a3);
        *(ushort4*)&fmaxb[((size_t)(o >> 5) * NBM + bm) * 32 + (o & 31)] = u;
      }
    }
  }
}

// ---------------- fmb = W2[:, :256] @ fmax  (512 x 4096), unroll-2 ----------------
__global__ __launch_bounds__(256) void k_fmb(
    const u16* __restrict__ wA, const u16* __restrict__ fmaxb, float* __restrict__ fmb)
{
  __shared__ alignas(16) u16 As[4096], As2[4096];
  __shared__ alignas(16) u16 Bs[4096], Bs2[4096];
  const int tid = threadIdx.x;
  const int oT = blockIdx.x & 3, cT = blockIdx.x >> 2;
  const int lane = tid & 63, wv = tid >> 6;
  const int wrow = (wv >> 1) * 64, wcol = (wv & 1) * 64;
  const int l15 = lane & 15, l4 = lane >> 4;
  v4f32 acc[4][4];
  #pragma unroll
  for (int mi = 0; mi < 4; ++mi)
    #pragma unroll
    for (int ni = 0; ni < 4; ++ni) acc[mi][ni] = (v4f32){0.f,0.f,0.f,0.f};
  const int idx0 = tid, idx1 = 256 + tid;
  const int r0 = idx0 >> 2, sg0 = idx0 & 3, r1 = idx1 >> 2, sg1 = idx1 & 3;
  for (int kt = 0; kt < 8; kt += 2) {
    if (kt) __syncthreads();
    gl16(wA + (size_t)(oT*128 + r0) * 512 + kt*32 + sg0*8, &As[idx0 * 8]);
    gl16(wA + (size_t)(oT*128 + r1) * 512 + kt*32 + sg1*8, &As[idx1 * 8]);
    gl16(wA + (size_t)(oT*128 + r0) * 512 + (kt+1)*32 + sg0*8, &As2[idx0 * 8]);
    gl16(wA + (size_t)(oT*128 + r1) * 512 + (kt+1)*32 + sg1*8, &As2[idx1 * 8]);
    const size_t bb = (size_t)kt * NBM + (size_t)cT * 128;
    const size_t bb2 = (size_t)(kt+1) * NBM + (size_t)cT * 128;
    gl16(fmaxb + (bb + r0) * 32 + sg0 * 8, &Bs[idx0 * 8]);
    gl16(fmaxb + (bb + r1) * 32 + sg1 * 8, &Bs[idx1 * 8]);
    gl16(fmaxb + (bb2 + r0) * 32 + sg0 * 8, &Bs2[idx0 * 8]);
    gl16(fmaxb + (bb2 + r1) * 32 + sg1 * 8, &Bs2[idx1 * 8]);
    asm volatile("s_waitcnt vmcnt(0)" ::: "memory");
    __syncthreads();
    MFMA_COMPUTE_P(As, Bs);
    MFMA_COMPUTE_P(As2, Bs2);
  }
  const int oB = oT*128 + wrow + l4*4;
  const int cB = cT*128 + wcol + l15;
  #pragma unroll
  for (int mi = 0; mi < 4; ++mi) {
    const int o = oB + mi*16;
    #pragma unroll
    for (int ni = 0; ni < 4; ++ni) {
      const int colg = cB + ni*16;
      fmb[(size_t)(o+0)*NBM + colg] = acc[mi][ni][0];
      fmb[(size_t)(o+1)*NBM + colg] = acc[mi][ni][1];
      fmb[(size_t)(o+2)*NBM + colg] = acc[mi][ni][2];
      fmb[(size_t)(o+3)*NBM + colg] = acc[mi][ni][3];
    }
  }
}

// ---------------- GEMM3: h3 = W2[:,256:] @ h2 + fmb ; unroll-2 + partial stats ----------------
__global__ __launch_bounds__(256) void k_gemm3(
    const u16* __restrict__ wA, const u16* __restrict__ hin,
    const float* __restrict__ fmb, u16* __restrict__ h3,
    float* __restrict__ pS, float* __restrict__ pQ)
{
  __shared__ alignas(16) u16 As[4096], As2[4096];
  __shared__ alignas(16) u16 Bs[4096], Bs2[4096];
  __shared__ float sAl[128], sQl[128];
  const int tid = threadIdx.x;
  const int oT = blockIdx.x & 3, cT = blockIdx.x >> 2;
  const int lane = tid & 63, wv = tid >> 6;
  const int wrow = (wv >> 1) * 64, wcol = (wv & 1) * 64;
  const int l15 = lane & 15, l4 = lane >> 4;
  if (tid < 128) { sAl[tid] = 0.f; sQl[tid] = 0.f; }
  v4f32 acc[4][4];
  #pragma unroll
  for (int mi = 0; mi < 4; ++mi)
    #pragma unroll
    for (int ni = 0; ni < 4; ++ni) acc[mi][ni] = (v4f32){0.f,0.f,0.f,0.f};
  const int idx0 = tid, idx1 = 256 + tid;
  const int r0 = idx0 >> 2, sg0 = idx0 & 3, r1 = idx1 >> 2, sg1 = idx1 & 3;
  for (int kt = 0; kt < 8; kt += 2) {
    if (kt) __syncthreads();
    gl16(wA + (size_t)(oT*128 + r0) * 512 + 256 + kt*32 + sg0*8, &As[idx0 * 8]);
    gl16(wA + (size_t)(oT*128 + r1) * 512 + 256 + kt*32 + sg1*8, &As[idx1 * 8]);
    gl16(wA + (size_t)(oT*128 + r0) * 512 + 256 + (kt+1)*32 + sg0*8, &As2[idx0 * 8]);
    gl16(wA + (size_t)(oT*128 + r1) * 512 + 256 + (kt+1)*32 + sg1*8, &As2[idx1 * 8]);
    const size_t bb = (size_t)kt * LTOT + (size_t)cT * 128;
    const size_t bb2 = (size_t)(kt+1) * LTOT + (size_t)cT * 128;
    gl16(hin + (bb + r0) * 32 + sg0 * 8, &Bs[idx0 * 8]);
    gl16(hin + (bb + r1) * 32 + sg1 * 8, &Bs[idx1 * 8]);
    gl16(hin + (bb2 + r0) * 32 + sg0 * 8, &Bs2[idx0 * 8]);
    gl16(hin + (bb2 + r1) * 32 + sg1 * 8, &Bs2[idx1 * 8]);
    asm volatile("s_waitcnt vmcnt(0)" ::: "memory");
    __syncthreads();
    MFMA_COMPUTE_P(As, Bs);
    MFMA_COMPUTE_P(As2, Bs2);
  }
  const int oB = oT*128 + wrow + l4*4;
  const int cB = cT*128 + wcol + l15;
  #pragma unroll
  for (int mi = 0; mi < 4; ++mi) {
    const int o = oB + mi*16;
    const size_t rb = (size_t)(o >> 5) * LTOT * 32 + (o & 31);
    float st[4] = {0.f,0.f,0.f,0.f}, sq[4] = {0.f,0.f,0.f,0.f};
    #pragma unroll
    for (int hf = 0; hf < 2; ++hf) {
      const int bm = (cT*128 + wcol + hf*32) >> 5;
      float e0 = fmb[(size_t)(o+0)*NBM + bm];
      float e1 = fmb[(size_t)(o+1)*NBM + bm];
      float e2 = fmb[(size_t)(o+2)*NBM + bm];
      float e3 = fmb[(size_t)(o+3)*NBM + bm];
      #pragma unroll
      for (int nn = 0; nn < 2; ++nn) {
        const int ni = hf*2 + nn;
        float v0 = acc[mi][ni][0] + e0;
        float v1 = acc[mi][ni][1] + e1;
        float v2 = acc[mi][ni][2] + e2;
        float v3 = acc[mi][ni][3] + e3;
        st[0] += v0; sq[0] = fmaf(v0, v0, sq[0]);
        st[1] += v1; sq[1] = fmaf(v1, v1, sq[1]);
        st[2] += v2; sq[2] = fmaf(v2, v2, sq[2]);
        st[3] += v3; sq[3] = fmaf(v3, v3, sq[3]);
        ushort4 u;
        u.x = f2bf(v0); u.y = f2bf(v1); u.z = f2bf(v2); u.w = f2bf(v3);
        *(ushort4*)&h3[rb + (size_t)(cB + ni*16) * 32] = u;
      }
    }
    #pragma unroll
    for (int e = 0; e < 4; ++e) {
      float s = st[e], q = sq[e];
      #pragma unroll
      for (int off = 1; off < 16; off <<= 1) {
        s += __shfl_xor(s, off);
        q += __shfl_xor(q, off);
      }
      if (l15 == 0) {
        const int lch = wrow + l4*4 + mi*16 + e;   // channel-local 0..127
        atomicAdd(&sAl[lch], s);
        atomicAdd(&sQl[lch], q);
      }
    }
  }
  __syncthreads();
  if (tid < 128) {
    pS[(size_t)blockIdx.x * 128 + tid] = sAl[tid];
    pQ[(size_t)blockIdx.x * 128 + tid] = sQl[tid];
  }
}

// ---------------- GEMM4: out = max_k( W3 @ bnrelu(h3) + b3 ), unroll-2 ----------------
__global__ __launch_bounds__(256) void k_gemm4(
    const u16* __restrict__ wA, const u16* __restrict__ hin,
    const float* __restrict__ Sc, const float* __restrict__ Tc,
    const float* __restrict__ bias, float* __restrict__ outF)
{
  __shared__ alignas(16) u16 As[4096], As2[4096];
  __shared__ alignas(16) u16 Bs[4096], Bs2[4096];
  __shared__ float sS[512], sT[512];
  const int tid = threadIdx.x;
  sS[tid] = Sc[tid]; sT[tid] = Tc[tid];
  sS[tid+256] = Sc[tid+256]; sT[tid+256] = Tc[tid+256];
  const int oT = blockIdx.x & 1, cT = blockIdx.x >> 1;
  const int lane = tid & 63, wv = tid >> 6;
  const int wrow = (wv >> 1) * 64, wcol = (wv & 1) * 64;
  const int l15 = lane & 15, l4 = lane >> 4;
  v4f32 acc[4][4];
  #pragma unroll
  for (int mi = 0; mi < 4; ++mi)
    #pragma unroll
    for (int ni = 0; ni < 4; ++ni) acc[mi][ni] = (v4f32){0.f,0.f,0.f,0.f};
  const int idx0 = tid, idx1 = 256 + tid;
  const int r0 = idx0 >> 2, sg0 = idx0 & 3, r1 = idx1 >> 2, sg1 = idx1 & 3;
  __syncthreads();
  for (int kt = 0; kt < 16; kt += 2) {
    const size_t bb = (size_t)kt * LTOT + (size_t)cT * 128;
    const size_t bb2 = (size_t)(kt+1) * LTOT + (size_t)cT * 128;
    uint4 q0 = *(const uint4*)(hin + (bb + r0) * 32 + sg0 * 8);
    uint4 q1 = *(const uint4*)(hin + (bb + r1) * 32 + sg1 * 8);
    uint4 q2 = *(const uint4*)(hin + (bb2 + r0) * 32 + sg0 * 8);
    uint4 q3 = *(const uint4*)(hin + (bb2 + r1) * 32 + sg1 * 8);
    if (kt) __syncthreads();
    gl16(wA + (size_t)(oT*128 + r0) * 512 + kt*32 + sg0*8, &As[idx0 * 8]);
    gl16(wA + (size_t)(oT*128 + r1) * 512 + kt*32 + sg1*8, &As[idx1 * 8]);
    gl16(wA + (size_t)(oT*128 + r0) * 512 + (kt+1)*32 + sg0*8, &As2[idx0 * 8]);
    gl16(wA + (size_t)(oT*128 + r1) * 512 + (kt+1)*32 + sg1*8, &As2[idx1 * 8]);
    xf_store(Bs,  idx0, q0, kt*32 + sg0*8, sS, sT);
    xf_store(Bs,  idx1, q1, kt*32 + sg1*8, sS, sT);
    xf_store(Bs2, idx0, q2, (kt+1)*32 + sg0*8, sS, sT);
    xf_store(Bs2, idx1, q3, (kt+1)*32 + sg1*8, sS, sT);
    asm volatile("s_waitcnt vmcnt(0)" ::: "memory");
    __syncthreads();
    MFMA_COMPUTE_P(As, Bs);
    MFMA_COMPUTE_P(As2, Bs2);
  }
  const int oB = oT*128 + wrow + l4*4;
  #pragma unroll
  for (int mi = 0; mi < 4; ++mi) {
    const float4 bv = *(const float4*)&bias[oB + mi*16];
    #pragma unroll
    for (int ni = 0; ni < 4; ++ni) {
      acc[mi][ni][0] += bv.x; acc[mi][ni][1] += bv.y;
      acc[mi][ni][2] += bv.z; acc[mi][ni][3] += bv.w;
    }
  }
  #pragma unroll
  for (int g = 0; g < 2; ++g) {
    const int bm = (cT*128 + wcol + g*32) >> 5;
    const int bI = bm >> 9, mm = bm & 511;
    #pragma unroll
    for (int mi = 0; mi < 4; ++mi) {
      float a0 = fmaxf(acc[mi][2*g][0], acc[mi][2*g+1][0]);
      float a1 = fmaxf(acc[mi][2*g][1], acc[mi][2*g+1][1]);
      float a2 = fmaxf(acc[mi][2*g][2], acc[mi][2*g+1][2]);
      float a3 = fmaxf(acc[mi][2*g][3], acc[mi][2*g+1][3]);
      #pragma unroll
      for (int off = 1; off < 16; off <<= 1) {
        a0 = fmaxf(a0, __shfl_xor(a0, off));
        a1 = fmaxf(a1, __shfl_xor(a1, off));
        a2 = fmaxf(a2, __shfl_xor(a2, off));
        a3 = fmaxf(a3, __shfl_xor(a3, off));
      }
      if (l15 == 0) {
        const int o = oB + mi*16;
        outF[((size_t)bI*256 + o+0)*512 + mm] = a0;
        outF[((size_t)bI*256 + o+1)*512 + mm] = a1;
        outF[((size_t)bI*256 + o+2)*512 + mm] = a2;
        outF[((size_t)bI*256 + o+3)*512 + mm] = a3;
      }
    }
  }
}

extern "C" void kernel_launch(void* const* d_in, const int* in_sizes, int n_in,
                              void* d_out, int out_size, void* d_ws, size_t ws_size,
                              hipStream_t stream)
{
  (void)in_sizes; (void)n_in; (void)out_size; (void)ws_size;
  const float* p   = (const float*)d_in[0];
  const float* x   = (const float*)d_in[1];
  const float* W0  = (const float*)d_in[2];
  const float* g0  = (const float*)d_in[3];
  const float* be0 = (const float*)d_in[4];
  const float* W1  = (const float*)d_in[5];
  const float* b1  = (const float*)d_in[6];
  const float* W2  = (const float*)d_in[7];
  const float* g2  = (const float*)d_in[8];
  const float* be2 = (const float*)d_in[9];
  const float* W3  = (const float*)d_in[10];
  const float* b3  = (const float*)d_in[11];
  float* out  = (float*)d_out;
  float* outP = out;
  float* outC = out + 196608;
  float* outX = out + 208896;
  float* outF = out + 405504;
  char* ws = (char*)d_ws;
  u16* h2    = (u16*)(ws);                 // 67108864 B
  u16* h3    = (u16*)(ws + 67108864);      // 134217728 B
  u16* f0    = (u16*)(ws + 201326592);     // 1572864 B
  u16* fmaxb = (u16*)(ws + 202899456);     // 2097152 B
  float* fmb = (float*)(ws + 204996608);   // 8388608 B
  u16* w1b   = (u16*)(ws + 213385216);     // 131072 B
  u16* w2b   = (u16*)(ws + 213516288);     // 524288 B
  u16* w3b   = (u16*)(ws + 214040576);     // 262144 B
  int* idxb  = (int*)(ws + 214302720);     // 16384 B
  float* statz = (float*)(ws + 214319104); // 12288 B (zeroed each call by prep)
  float* cov  = statz;                 // 27 floats
  float* s0 = statz + 1536;   float* t0 = statz + 1792;
  float* s2 = statz + 2048;   float* t2 = statz + 2560;
  float* pS  = (float*)(ws + 214331392);   // 2097152 B  (4096 blocks x 128 ch)
  float* pQ  = (float*)(ws + 216428544);   // 2097152 B

  k_fps_prep<<<216, 512, 0, stream>>>(p, x, W1, W2, W3, outP, outC, outX,
                                      w1b, w2b, w3b, statz, idxb);
  k_group<<<1024, 256, 0, stream>>>(p, x, outC, idxb, f0);
  k_cov<<<512, 256, 0, stream>>>(f0, cov);
  k_fin1<<<1, 256, 0, stream>>>(cov, W0, g0, be0, s0, t0);
  k_gemm12<<<2048, 256, 0, stream>>>(w1b, f0, W0, s0, t0, b1, h2, fmaxb);
  k_fmb<<<128, 256, 0, stream>>>(w2b, fmaxb, fmb);
  k_gemm3<<<4096, 256, 0, stream>>>(w2b, h2, fmb, h3, pS, pQ);
  k_red<<<512, 256, 0, stream>>>(pS, pQ, g2, be2, s2, t2);
  k_gemm4<<<2048, 256, 0, stream>>>(w3b, h3, s2, t2, b3, outF);
}

// Round 12
// 768.022 us; speedup vs baseline: 1.0331x; 1.0331x over previous
//
#include <hip/hip_runtime.h>

typedef unsigned short u16;
typedef unsigned int u32;
typedef unsigned long long u64;
typedef __bf16 bf16x8 __attribute__((ext_vector_type(8)));
typedef float v4f32 __attribute__((ext_vector_type(4)));

#define NP 8192
#define NM 512
#define LTOT 131072
#define NBM 4096
#define R2F 0.009999999776482582f   // float(0.1*0.1)

__device__ __forceinline__ float bf2f(u16 u) { return __uint_as_float(((u32)u) << 16); }
__device__ __forceinline__ u16 f2bf(float f) {
  u32 u = __float_as_uint(f);
  return (u16)((u + 0x7fffu + ((u >> 16) & 1u)) >> 16);
}
__device__ __forceinline__ void gl16(const void* g, void* l) {
  __builtin_amdgcn_global_load_lds((const __attribute__((address_space(1))) u32*)g,
                                   (__attribute__((address_space(3))) u32*)l, 16, 0, 0);
}

// wave64 max of u64 keys via DPP ladder; lane 63 ends with the full max.
__device__ __forceinline__ u64 wave_max64_dpp(u64 k) {
#define DPP_STEP(CTRL) { \
    u32 lo_ = (u32)__builtin_amdgcn_update_dpp(0, (int)(u32)k, CTRL, 0xF, 0xF, true); \
    u32 hi_ = (u32)__builtin_amdgcn_update_dpp(0, (int)(u32)(k >> 32), CTRL, 0xF, 0xF, true); \
    u64 o_ = ((u64)hi_ << 32) | lo_; \
    if (o_ > k) k = o_; }
  DPP_STEP(0x111)  // row_shr:1
  DPP_STEP(0x112)  // row_shr:2
  DPP_STEP(0x114)  // row_shr:4
  DPP_STEP(0x118)  // row_shr:8
  DPP_STEP(0x142)  // row_bcast:15
  DPP_STEP(0x143)  // row_bcast:31
#undef DPP_STEP
  return k;
}

#define MFMA_COMPUTE_P(ASP, BSP) do { \
  bf16x8 a_[4], b_[4]; \
  _Pragma("unroll") \
  for (int mi_ = 0; mi_ < 4; ++mi_) a_[mi_] = *(const bf16x8*)&(ASP)[(wrow + mi_*16 + l15)*32 + l4*8]; \
  _Pragma("unroll") \
  for (int ni_ = 0; ni_ < 4; ++ni_) b_[ni_] = *(const bf16x8*)&(BSP)[(wcol + ni_*16 + l15)*32 + l4*8]; \
  _Pragma("unroll") \
  for (int mi_ = 0; mi_ < 4; ++mi_) { \
    _Pragma("unroll") \
    for (int ni_ = 0; ni_ < 4; ++ni_) \
      acc[mi_][ni_] = __builtin_amdgcn_mfma_f32_16x16x32_bf16(a_[mi_], b_[ni_], acc[mi_][ni_], 0, 0, 0); \
  } \
} while (0)

// ---------------- FPS (blocks 0..7) + prep work (blocks 8..215) ----------------
// Measured-best (471-474us in R10): 512 threads x 16 pts/thread, SCALAR exact
// distances, thread tree-max + bit-exact scan, u64 key DPP reduce, leader LDS
// atomic_max into rotating slot, 1 barrier/step. pk-f32 variant measured SLOWER
// (497us, R11). FROZEN — do not touch.
__global__ __launch_bounds__(512) void k_fps_prep(
    const float* __restrict__ p, const float* __restrict__ x,
    const float* __restrict__ W1, const float* __restrict__ W2, const float* __restrict__ W3,
    float* __restrict__ outP, float* __restrict__ outC, float* __restrict__ outX,
    u16* __restrict__ w1b, u16* __restrict__ w2b, u16* __restrict__ w3b,
    float* __restrict__ statz, int* __restrict__ idxb)
{
  const int tid = threadIdx.x;
  if (blockIdx.x >= 8) {
    for (size_t i = (size_t)(blockIdx.x - 8) * 512 + tid; i < 855040; i += 208 * 512) {
      if (i < 196608)      outP[i] = p[i];
      else if (i < 393216) outX[i - 196608] = x[i - 196608];
      else if (i < 458752) w1b[i - 393216] = f2bf(W1[i - 393216]);
      else if (i < 720896) w2b[i - 458752] = f2bf(W2[i - 458752]);
      else if (i < 851968) w3b[i - 720896] = f2bf(W3[i - 720896]);
      else                 statz[i - 851968] = 0.0f;
    }
    return;
  }
  const int b = blockIdx.x;
  const float* pb = p + (size_t)b * NP * 3;
  __shared__ float pl[NP * 3];
  __shared__ u64 slot[3];
  float px[16], py[16], pz[16], md[16];
  u32 nj[16];
  #pragma unroll
  for (int q = 0; q < 16; ++q) {
    int j = tid + (q << 9);
    float a0 = pb[j*3+0], a1 = pb[j*3+1], a2 = pb[j*3+2];
    px[q] = a0; py[q] = a1; pz[q] = a2; md[q] = 1e10f;
    nj[q] = ~(u32)j;
    pl[j*3+0] = a0; pl[j*3+1] = a1; pl[j*3+2] = a2;
  }
  if (tid < 3) slot[tid] = 0ull;
  __syncthreads();
  int last = 0;
  float* ctr = outC + (size_t)b * NM * 3;
  int* ip = idxb + b * NM;
  for (int s = 0; s < NM; ++s) {
    const int sl = s % 3;
    float lx = pl[last*3], ly = pl[last*3+1], lz = pl[last*3+2];
    if (tid == 0) {
      ip[s] = last; ctr[s*3] = lx; ctr[s*3+1] = ly; ctr[s*3+2] = lz;
      slot[(s+1) % 3] = 0ull;   // safe: its readers finished 2 barriers ago
    }
    #pragma unroll
    for (int q = 0; q < 16; ++q) {
      float dx = __fsub_rn(px[q], lx), dy = __fsub_rn(py[q], ly), dz = __fsub_rn(pz[q], lz);
      float d = __fadd_rn(__fadd_rn(__fmul_rn(dx,dx), __fmul_rn(dy,dy)), __fmul_rn(dz,dz));
      md[q] = fminf(md[q], d);
    }
    float t0 = fmaxf(fmaxf(md[0], md[1]),  fmaxf(md[2], md[3]));
    float t1 = fmaxf(fmaxf(md[4], md[5]),  fmaxf(md[6], md[7]));
    float t2 = fmaxf(fmaxf(md[8], md[9]),  fmaxf(md[10], md[11]));
    float t3 = fmaxf(fmaxf(md[12], md[13]), fmaxf(md[14], md[15]));
    float tmax = fmaxf(fmaxf(t0, t1), fmaxf(t2, t3));
    u32 tb = __float_as_uint(tmax);
    u32 cand = 0;
    #pragma unroll
    for (int q = 0; q < 16; ++q) {
      u32 c = (__float_as_uint(md[q]) == tb) ? nj[q] : 0u;
      cand = c > cand ? c : cand;
    }
    u64 key = wave_max64_dpp(((u64)tb << 32) | (u64)cand);
    u32 klo = (u32)__builtin_amdgcn_readlane((int)(u32)key, 63);
    u32 khi = (u32)__builtin_amdgcn_readlane((int)(u32)(key >> 32), 63);
    if ((tid & 63) == 0)
      __hip_atomic_fetch_max(&slot[sl], ((u64)khi << 32) | klo,
                             __ATOMIC_RELAXED, __HIP_MEMORY_SCOPE_WORKGROUP);
    __syncthreads();
    last = (int)(~(u32)(slot[sl] & 0xffffffffull));
  }
}

// ---------------- ball query + gather: one wave per center ----------------
__global__ __launch_bounds__(256) void k_group(
    const float* __restrict__ p, const float* __restrict__ x,
    const float* __restrict__ ctr, const int* __restrict__ idxb,
    u16* __restrict__ f0)
{
  const int tid = threadIdx.x, wv = tid >> 6, lane = tid & 63;
  const int cm = blockIdx.x * 4 + wv;
  const int b = cm >> 9;
  __shared__ int selS[4][33];
  volatile int* sel = selS[wv];
  const float cx0 = ctr[cm*3+0], cy0 = ctr[cm*3+1], cz0 = ctr[cm*3+2];
  const float* pb = p + (size_t)b * NP * 3;
  int cnt = 0;
  for (int ch = 0; ch < NP/64; ++ch) {
    if (cnt >= 32) break;
    int j = (ch << 6) + lane;
    float qx = pb[j*3], qy = pb[j*3+1], qz = pb[j*3+2];
    float dx = __fsub_rn(cx0,qx), dy = __fsub_rn(cy0,qy), dz = __fsub_rn(cz0,qz);
    float d2 = __fadd_rn(__fadd_rn(__fmul_rn(dx,dx),__fmul_rn(dy,dy)),__fmul_rn(dz,dz));
    bool pr = d2 < R2F;
    u64 msk = __ballot(pr);
    int pos = cnt + (int)__popcll(msk & ((1ull << lane) - 1ull));
    if (pr && pos < 32) sel[pos] = j;
    cnt += (int)__popcll(msk);
  }
  if (lane < 32) {
    int jj = (lane < cnt) ? sel[lane] : sel[0];
    const float* xb = x + (size_t)b * 3 * NP;
    int ic = idxb[cm];
    float gx = pb[jj*3], gy = pb[jj*3+1], gz = pb[jj*3+2];
    size_t col = (size_t)cm * 32 + lane;
    f0[0*(size_t)LTOT + col] = f2bf(gx - cx0);
    f0[1*(size_t)LTOT + col] = f2bf(gy - cy0);
    f0[2*(size_t)LTOT + col] = f2bf(gz - cz0);
    f0[3*(size_t)LTOT + col] = f2bf(xb[jj]      - xb[ic]);
    f0[4*(size_t)LTOT + col] = f2bf(xb[NP+jj]   - xb[NP+ic]);
    f0[5*(size_t)LTOT + col] = f2bf(xb[2*NP+jj] - xb[2*NP+ic]);
  }
}

// ---------------- second-moment stats of f0 (6 sums + 21 upper-tri products) ----------------
__global__ __launch_bounds__(256) void k_cov(const u16* __restrict__ f0, float* __restrict__ cov)
{
  const int tid = threadIdx.x;
  const size_t col = (size_t)blockIdx.x * 256 + tid;
  float f[6];
  #pragma unroll
  for (int c = 0; c < 6; ++c) f[c] = bf2f(f0[(size_t)c * LTOT + col]);
  float v[27];
  int n = 0;
  #pragma unroll
  for (int c = 0; c < 6; ++c) v[n++] = f[c];
  #pragma unroll
  for (int i = 0; i < 6; ++i)
    #pragma unroll
    for (int j = i; j < 6; ++j) v[n++] = f[i] * f[j];
  #pragma unroll
  for (int k = 0; k < 27; ++k) {
    float s = v[k];
    #pragma unroll
    for (int off = 1; off < 64; off <<= 1) s += __shfl_xor(s, off);
    v[k] = s;
  }
  __shared__ float ls[27];
  if (tid < 27) ls[tid] = 0.f;
  __syncthreads();
  if ((tid & 63) == 0) {
    #pragma unroll
    for (int k = 0; k < 27; ++k) atomicAdd(&ls[k], v[k]);
  }
  __syncthreads();
  if (tid < 27) atomicAdd(&cov[tid], ls[tid]);
}

// analytic BN params for h1 = W0 @ f0 : mu = W0 m, E2 = w^T (Sff/N) w
__global__ void k_fin1(const float* __restrict__ cov, const float* __restrict__ W0,
                       const float* __restrict__ g, const float* __restrict__ be,
                       float* __restrict__ S, float* __restrict__ T)
{
  int c = threadIdx.x;   // 256 channels
  const float inv = 1.0f / 131072.0f;
  float w[6];
  #pragma unroll
  for (int k = 0; k < 6; ++k) w[k] = W0[c*6 + k];
  float mu = 0.f;
  #pragma unroll
  for (int k = 0; k < 6; ++k) mu = fmaf(w[k], cov[k], mu);
  mu *= inv;
  float e2 = 0.f;
  int n = 6;
  #pragma unroll
  for (int i = 0; i < 6; ++i)
    #pragma unroll
    for (int j = i; j < 6; ++j) {
      float coeff = (i == j) ? w[i]*w[j] : 2.f*w[i]*w[j];
      e2 = fmaf(coeff, cov[n++] * inv, e2);
    }
  float var = e2 - mu * mu;
  float s = g[c] / sqrtf(var + 1e-5f);
  S[c] = s; T[c] = be[c] - mu * s;
}

// ---------------- reduce gemm3's per-block partial stats -> BN params for h3 ----------------
__global__ __launch_bounds__(256) void k_red(
    const float* __restrict__ pS, const float* __restrict__ pQ,
    const float* __restrict__ g, const float* __restrict__ be,
    float* __restrict__ S, float* __restrict__ T)
{
  const int c = blockIdx.x;            // 512 channels
  const int tid = threadIdx.x;
  const int oTc = c >> 7, lc = c & 127;
  float s = 0.f, q = 0.f;
  for (int j = tid; j < 1024; j += 256) {      // 1024 cT blocks with this oT
    size_t idx = (size_t)(j * 4 + oTc) * 128 + lc;
    s += pS[idx]; q += pQ[idx];
  }
  #pragma unroll
  for (int off = 1; off < 64; off <<= 1) { s += __shfl_xor(s, off); q += __shfl_xor(q, off); }
  __shared__ float ls[4], lq[4];
  if ((tid & 63) == 0) { ls[tid >> 6] = s; lq[tid >> 6] = q; }
  __syncthreads();
  if (tid == 0) {
    float ss = ls[0] + ls[1] + ls[2] + ls[3];
    float qq = lq[0] + lq[1] + lq[2] + lq[3];
    const float inv = 1.0f / 131072.0f;
    float mu = ss * inv;
    float var = qq * inv - mu * mu;
    float sc = g[c] / sqrtf(var + 1e-5f);
    S[c] = sc; T[c] = be[c] - mu * sc;
  }
}

// affine+relu transform of an 8-element bf16 chunk, store to LDS
__device__ __forceinline__ void xf_store(u16* Bs, int idx, uint4 q, int cb,
                                         const float* sS, const float* sT)
{
  u32 w[4]; u32 qa[4] = {q.x, q.y, q.z, q.w};
  #pragma unroll
  for (int t2 = 0; t2 < 4; ++t2) {
    float a  = fmaxf(fmaf(sS[cb + 2*t2],     bf2f((u16)(qa[t2] & 0xffffu)), sT[cb + 2*t2]), 0.f);
    float bv = fmaxf(fmaf(sS[cb + 2*t2 + 1], bf2f((u16)(qa[t2] >> 16)),     sT[cb + 2*t2 + 1]), 0.f);
    w[t2] = (u32)f2bf(a) | ((u32)f2bf(bv) << 16);
  }
  *(uint4*)&Bs[idx * 8] = make_uint4(w[0], w[1], w[2], w[3]);
}

// ---------------- GEMM12: fused conv1 — h2 = W1 @ bnrelu(W0@f0) + b1 ; fmax ----------------
__global__ __launch_bounds__(256) void k_gemm12(
    const u16* __restrict__ wA, const u16* __restrict__ f0,
    const float* __restrict__ W0,
    const float* __restrict__ Sc, const float* __restrict__ Tc,
    const float* __restrict__ bias,
    u16* __restrict__ h2, u16* __restrict__ fmaxb)
{
  __shared__ alignas(16) u16 As[4096], As2[4096];
  __shared__ alignas(16) u16 Bs[4096], Bs2[4096];
  __shared__ float w0l[1536];
  __shared__ float sS[256], sT[256];
  const int tid = threadIdx.x;
  sS[tid] = Sc[tid]; sT[tid] = Tc[tid];
  for (int i = tid; i < 1536; i += 256) w0l[i] = W0[i];
  const int oT = blockIdx.x & 1, cT = blockIdx.x >> 1;
  const int lane = tid & 63, wv = tid >> 6;
  const int wrow = (wv >> 1) * 64, wcol = (wv & 1) * 64;
  const int l15 = lane & 15, l4 = lane >> 4;
  const int myc = tid >> 1;                       // 0..127
  const int ch0 = (tid & 1) * 16;                 // 0 or 16
  const size_t gcol = (size_t)cT * 128 + myc;
  float fin[6];
  #pragma unroll
  for (int c = 0; c < 6; ++c) fin[c] = bf2f(f0[(size_t)c * LTOT + gcol]);
  v4f32 acc[4][4];
  #pragma unroll
  for (int mi = 0; mi < 4; ++mi)
    #pragma unroll
    for (int ni = 0; ni < 4; ++ni) acc[mi][ni] = (v4f32){0.f,0.f,0.f,0.f};
  const int idx0 = tid, idx1 = 256 + tid;
  const int r0 = idx0 >> 2, sg0 = idx0 & 3, r1 = idx1 >> 2, sg1 = idx1 & 3;
  __syncthreads();   // w0l, sS/sT visible
  for (int kt = 0; kt < 8; kt += 2) {
    if (kt) __syncthreads();
    gl16(wA + (size_t)(oT*128 + r0) * 256 + kt*32 + sg0*8, &As[idx0 * 8]);
    gl16(wA + (size_t)(oT*128 + r1) * 256 + kt*32 + sg1*8, &As[idx1 * 8]);
    gl16(wA + (size_t)(oT*128 + r0) * 256 + (kt+1)*32 + sg0*8, &As2[idx0 * 8]);
    gl16(wA + (size_t)(oT*128 + r1) * 256 + (kt+1)*32 + sg1*8, &As2[idx1 * 8]);
    #pragma unroll
    for (int half = 0; half < 2; ++half) {
      u16* Bdst = half ? Bs2 : Bs;
      u32 wp[8];
      #pragma unroll
      for (int j = 0; j < 16; j += 2) {
        const int o0 = (kt + half)*32 + ch0 + j;
        float v0 = 0.f, v1 = 0.f;
        #pragma unroll
        for (int c = 0; c < 6; ++c) {
          v0 = fmaf(w0l[o0*6 + c], fin[c], v0);
          v1 = fmaf(w0l[(o0+1)*6 + c], fin[c], v1);
        }
        float h0 = bf2f(f2bf(v0)), h1v = bf2f(f2bf(v1));
        float a0 = fmaxf(fmaf(sS[o0],     h0,  sT[o0]),     0.f);
        float a1 = fmaxf(fmaf(sS[o0 + 1], h1v, sT[o0 + 1]), 0.f);
        wp[j >> 1] = (u32)f2bf(a0) | ((u32)f2bf(a1) << 16);
      }
      *(uint4*)&Bdst[myc*32 + ch0]     = make_uint4(wp[0], wp[1], wp[2], wp[3]);
      *(uint4*)&Bdst[myc*32 + ch0 + 8] = make_uint4(wp[4], wp[5], wp[6], wp[7]);
    }
    asm volatile("s_waitcnt vmcnt(0)" ::: "memory");
    __syncthreads();
    MFMA_COMPUTE_P(As, Bs);
    MFMA_COMPUTE_P(As2, Bs2);
  }
  const int oB = oT*128 + wrow + l4*4;
  const int cB = cT*128 + wcol + l15;
  #pragma unroll
  for (int mi = 0; mi < 4; ++mi) {
    const float4 bv = *(const float4*)&bias[oB + mi*16];
    #pragma unroll
    for (int ni = 0; ni < 4; ++ni) {
      acc[mi][ni][0] += bv.x; acc[mi][ni][1] += bv.y;
      acc[mi][ni][2] += bv.z; acc[mi][ni][3] += bv.w;
    }
  }
  #pragma unroll
  for (int mi = 0; mi < 4; ++mi) {
    const int o = oB + mi*16;
    const size_t rb = (size_t)(o >> 5) * LTOT * 32 + (o & 31);
    #pragma unroll
    for (int ni = 0; ni < 4; ++ni) {
      ushort4 u; u.x = f2bf(acc[mi][ni][0]); u.y = f2bf(acc[mi][ni][1]);
      u.z = f2bf(acc[mi][ni][2]); u.w = f2bf(acc[mi][ni][3]);
      *(ushort4*)&h2[rb + (size_t)(cB + ni*16) * 32] = u;
    }
  }
  #pragma unroll
  for (int g = 0; g < 2; ++g) {
    const int bm = (cT*128 + wcol + g*32) >> 5;
    #pragma unroll
    for (int mi = 0; mi < 4; ++mi) {
      float a0 = fmaxf(acc[mi][2*g][0], acc[mi][2*g+1][0]);
      float a1 = fmaxf(acc[mi][2*g][1], acc[mi][2*g+1][1]);
      float a2 = fmaxf(acc[mi][2*g][2], acc[mi][2*g+1][2]);
      float a3 = fmaxf(acc[mi][2*g][3], acc[mi][2*g+1][3]);
      #pragma unroll
      for (int off = 1; off < 16; off <<= 1) {
        a0 = fmaxf(a0, __shfl_xor(a0, off));
        a1 = fmaxf(a1, __shfl_xor(a1, off));
        a2 = fmaxf(a2, __shfl_xor(a2, off));
        a3 = fmaxf(a3, __shfl_xor(a3, off));
      }
      if (l15 == 0) {
        const int o = oB + mi*16;
        ushort4 u; u.x=f2bf(a0); u.y=f2bf(a1); u.z=f2bf(a2); u.w=f2bf(a3);
        *(ushort4*)&fmaxb[((size_t)(o >> 5) * NBM + bm) * 32 + (o & 31)] = u;
      }
    }
  }
}

// ---------------- fmb = W2[:, :256] @ fmax  (512 x 4096), unroll-2 ----------------
__global__ __launch_bounds__(256) void k_fmb(
    const u16* __restrict__ wA, const u16* __restrict__ fmaxb, float* __restrict__ fmb)
{
  __shared__ alignas(16) u16 As[4096], As2[4096];
  __shared__ alignas(16) u16 Bs[4096], Bs2[4096];
  const int tid = threadIdx.x;
  const int oT = blockIdx.x & 3, cT = blockIdx.x >> 2;
  const int lane = tid & 63, wv = tid >> 6;
  const int wrow = (wv >> 1) * 64, wcol = (wv & 1) * 64;
  const int l15 = lane & 15, l4 = lane >> 4;
  v4f32 acc[4][4];
  #pragma unroll
  for (int mi = 0; mi < 4; ++mi)
    #pragma unroll
    for (int ni = 0; ni < 4; ++ni) acc[mi][ni] = (v4f32){0.f,0.f,0.f,0.f};
  const int idx0 = tid, idx1 = 256 + tid;
  const int r0 = idx0 >> 2, sg0 = idx0 & 3, r1 = idx1 >> 2, sg1 = idx1 & 3;
  for (int kt = 0; kt < 8; kt += 2) {
    if (kt) __syncthreads();
    gl16(wA + (size_t)(oT*128 + r0) * 512 + kt*32 + sg0*8, &As[idx0 * 8]);
    gl16(wA + (size_t)(oT*128 + r1) * 512 + kt*32 + sg1*8, &As[idx1 * 8]);
    gl16(wA + (size_t)(oT*128 + r0) * 512 + (kt+1)*32 + sg0*8, &As2[idx0 * 8]);
    gl16(wA + (size_t)(oT*128 + r1) * 512 + (kt+1)*32 + sg1*8, &As2[idx1 * 8]);
    const size_t bb = (size_t)kt * NBM + (size_t)cT * 128;
    const size_t bb2 = (size_t)(kt+1) * NBM + (size_t)cT * 128;
    gl16(fmaxb + (bb + r0) * 32 + sg0 * 8, &Bs[idx0 * 8]);
    gl16(fmaxb + (bb + r1) * 32 + sg1 * 8, &Bs[idx1 * 8]);
    gl16(fmaxb + (bb2 + r0) * 32 + sg0 * 8, &Bs2[idx0 * 8]);
    gl16(fmaxb + (bb2 + r1) * 32 + sg1 * 8, &Bs2[idx1 * 8]);
    asm volatile("s_waitcnt vmcnt(0)" ::: "memory");
    __syncthreads();
    MFMA_COMPUTE_P(As, Bs);
    MFMA_COMPUTE_P(As2, Bs2);
  }
  const int oB = oT*128 + wrow + l4*4;
  const int cB = cT*128 + wcol + l15;
  #pragma unroll
  for (int mi = 0; mi < 4; ++mi) {
    const int o = oB + mi*16;
    #pragma unroll
    for (int ni = 0; ni < 4; ++ni) {
      const int colg = cB + ni*16;
      fmb[(size_t)(o+0)*NBM + colg] = acc[mi][ni][0];
      fmb[(size_t)(o+1)*NBM + colg] = acc[mi][ni][1];
      fmb[(size_t)(o+2)*NBM + colg] = acc[mi][ni][2];
      fmb[(size_t)(o+3)*NBM + colg] = acc[mi][ni][3];
    }
  }
}

// ---------------- GEMM3: h3 = W2[:,256:] @ h2 + fmb ; unroll-2 + partial stats ----------------
__global__ __launch_bounds__(256) void k_gemm3(
    const u16* __restrict__ wA, const u16* __restrict__ hin,
    const float* __restrict__ fmb, u16* __restrict__ h3,
    float* __restrict__ pS, float* __restrict__ pQ)
{
  __shared__ alignas(16) u16 As[4096], As2[4096];
  __shared__ alignas(16) u16 Bs[4096], Bs2[4096];
  __shared__ float sAl[128], sQl[128];
  const int tid = threadIdx.x;
  const int oT = blockIdx.x & 3, cT = blockIdx.x >> 2;
  const int lane = tid & 63, wv = tid >> 6;
  const int wrow = (wv >> 1) * 64, wcol = (wv & 1) * 64;
  const int l15 = lane & 15, l4 = lane >> 4;
  if (tid < 128) { sAl[tid] = 0.f; sQl[tid] = 0.f; }
  v4f32 acc[4][4];
  #pragma unroll
  for (int mi = 0; mi < 4; ++mi)
    #pragma unroll
    for (int ni = 0; ni < 4; ++ni) acc[mi][ni] = (v4f32){0.f,0.f,0.f,0.f};
  const int idx0 = tid, idx1 = 256 + tid;
  const int r0 = idx0 >> 2, sg0 = idx0 & 3, r1 = idx1 >> 2, sg1 = idx1 & 3;
  for (int kt = 0; kt < 8; kt += 2) {
    if (kt) __syncthreads();
    gl16(wA + (size_t)(oT*128 + r0) * 512 + 256 + kt*32 + sg0*8, &As[idx0 * 8]);
    gl16(wA + (size_t)(oT*128 + r1) * 512 + 256 + kt*32 + sg1*8, &As[idx1 * 8]);
    gl16(wA + (size_t)(oT*128 + r0) * 512 + 256 + (kt+1)*32 + sg0*8, &As2[idx0 * 8]);
    gl16(wA + (size_t)(oT*128 + r1) * 512 + 256 + (kt+1)*32 + sg1*8, &As2[idx1 * 8]);
    const size_t bb = (size_t)kt * LTOT + (size_t)cT * 128;
    const size_t bb2 = (size_t)(kt+1) * LTOT + (size_t)cT * 128;
    gl16(hin + (bb + r0) * 32 + sg0 * 8, &Bs[idx0 * 8]);
    gl16(hin + (bb + r1) * 32 + sg1 * 8, &Bs[idx1 * 8]);
    gl16(hin + (bb2 + r0) * 32 + sg0 * 8, &Bs2[idx0 * 8]);
    gl16(hin + (bb2 + r1) * 32 + sg1 * 8, &Bs2[idx1 * 8]);
    asm volatile("s_waitcnt vmcnt(0)" ::: "memory");
    __syncthreads();
    MFMA_COMPUTE_P(As, Bs);
    MFMA_COMPUTE_P(As2, Bs2);
  }
  const int oB = oT*128 + wrow + l4*4;
  const int cB = cT*128 + wcol + l15;
  #pragma unroll
  for (int mi = 0; mi < 4; ++mi) {
    const int o = oB + mi*16;
    const size_t rb = (size_t)(o >> 5) * LTOT * 32 + (o & 31);
    float st[4] = {0.f,0.f,0.f,0.f}, sq[4] = {0.f,0.f,0.f,0.f};
    #pragma unroll
    for (int hf = 0; hf < 2; ++hf) {
      const int bm = (cT*128 + wcol + hf*32) >> 5;
      float e0 = fmb[(size_t)(o+0)*NBM + bm];
      float e1 = fmb[(size_t)(o+1)*NBM + bm];
      float e2 = fmb[(size_t)(o+2)*NBM + bm];
      float e3 = fmb[(size_t)(o+3)*NBM + bm];
      #pragma unroll
      for (int nn = 0; nn < 2; ++nn) {
        const int ni = hf*2 + nn;
        float v0 = acc[mi][ni][0] + e0;
        float v1 = acc[mi][ni][1] + e1;
        float v2 = acc[mi][ni][2] + e2;
        float v3 = acc[mi][ni][3] + e3;
        st[0] += v0; sq[0] = fmaf(v0, v0, sq[0]);
        st[1] += v1; sq[1] = fmaf(v1, v1, sq[1]);
        st[2] += v2; sq[2] = fmaf(v2, v2, sq[2]);
        st[3] += v3; sq[3] = fmaf(v3, v3, sq[3]);
        ushort4 u;
        u.x = f2bf(v0); u.y = f2bf(v1); u.z = f2bf(v2); u.w = f2bf(v3);
        *(ushort4*)&h3[rb + (size_t)(cB + ni*16) * 32] = u;
      }
    }
    #pragma unroll
    for (int e = 0; e < 4; ++e) {
      float s = st[e], q = sq[e];
      #pragma unroll
      for (int off = 1; off < 16; off <<= 1) {
        s += __shfl_xor(s, off);
        q += __shfl_xor(q, off);
      }
      if (l15 == 0) {
        const int lch = wrow + l4*4 + mi*16 + e;   // channel-local 0..127
        atomicAdd(&sAl[lch], s);
        atomicAdd(&sQl[lch], q);
      }
    }
  }
  __syncthreads();
  if (tid < 128) {
    pS[(size_t)blockIdx.x * 128 + tid] = sAl[tid];
    pQ[(size_t)blockIdx.x * 128 + tid] = sQl[tid];
  }
}

// ---------------- GEMM4: out = max_k( W3 @ bnrelu(h3) + b3 ), unroll-2 ----------------
__global__ __launch_bounds__(256) void k_gemm4(
    const u16* __restrict__ wA, const u16* __restrict__ hin,
    const float* __restrict__ Sc, const float* __restrict__ Tc,
    const float* __restrict__ bias, float* __restrict__ outF)
{
  __shared__ alignas(16) u16 As[4096], As2[4096];
  __shared__ alignas(16) u16 Bs[4096], Bs2[4096];
  __shared__ float sS[512], sT[512];
  const int tid = threadIdx.x;
  sS[tid] = Sc[tid]; sT[tid] = Tc[tid];
  sS[tid+256] = Sc[tid+256]; sT[tid+256] = Tc[tid+256];
  const int oT = blockIdx.x & 1, cT = blockIdx.x >> 1;
  const int lane = tid & 63, wv = tid >> 6;
  const int wrow = (wv >> 1) * 64, wcol = (wv & 1) * 64;
  const int l15 = lane & 15, l4 = lane >> 4;
  v4f32 acc[4][4];
  #pragma unroll
  for (int mi = 0; mi < 4; ++mi)
    #pragma unroll
    for (int ni = 0; ni < 4; ++ni) acc[mi][ni] = (v4f32){0.f,0.f,0.f,0.f};
  const int idx0 = tid, idx1 = 256 + tid;
  const int r0 = idx0 >> 2, sg0 = idx0 & 3, r1 = idx1 >> 2, sg1 = idx1 & 3;
  __syncthreads();
  for (int kt = 0; kt < 16; kt += 2) {
    const size_t bb = (size_t)kt * LTOT + (size_t)cT * 128;
    const size_t bb2 = (size_t)(kt+1) * LTOT + (size_t)cT * 128;
    uint4 q0 = *(const uint4*)(hin + (bb + r0) * 32 + sg0 * 8);
    uint4 q1 = *(const uint4*)(hin + (bb + r1) * 32 + sg1 * 8);
    uint4 q2 = *(const uint4*)(hin + (bb2 + r0) * 32 + sg0 * 8);
    uint4 q3 = *(const uint4*)(hin + (bb2 + r1) * 32 + sg1 * 8);
    if (kt) __syncthreads();
    gl16(wA + (size_t)(oT*128 + r0) * 512 + kt*32 + sg0*8, &As[idx0 * 8]);
    gl16(wA + (size_t)(oT*128 + r1) * 512 + kt*32 + sg1*8, &As[idx1 * 8]);
    gl16(wA + (size_t)(oT*128 + r0) * 512 + (kt+1)*32 + sg0*8, &As2[idx0 * 8]);
    gl16(wA + (size_t)(oT*128 + r1) * 512 + (kt+1)*32 + sg1*8, &As2[idx1 * 8]);
    xf_store(Bs,  idx0, q0, kt*32 + sg0*8, sS, sT);
    xf_store(Bs,  idx1, q1, kt*32 + sg1*8, sS, sT);
    xf_store(Bs2, idx0, q2, (kt+1)*32 + sg0*8, sS, sT);
    xf_store(Bs2, idx1, q3, (kt+1)*32 + sg1*8, sS, sT);
    asm volatile("s_waitcnt vmcnt(0)" ::: "memory");
    __syncthreads();
    MFMA_COMPUTE_P(As, Bs);
    MFMA_COMPUTE_P(As2, Bs2);
  }
  const int oB = oT*128 + wrow + l4*4;
  #pragma unroll
  for (int mi = 0; mi < 4; ++mi) {
    const float4 bv = *(const float4*)&bias[oB + mi*16];
    #pragma unroll
    for (int ni = 0; ni < 4; ++ni) {
      acc[mi][ni][0] += bv.x; acc[mi][ni][1] += bv.y;
      acc[mi][ni][2] += bv.z; acc[mi][ni][3] += bv.w;
    }
  }
  #pragma unroll
  for (int g = 0; g < 2; ++g) {
    const int bm = (cT*128 + wcol + g*32) >> 5;
    const int bI = bm >> 9, mm = bm & 511;
    #pragma unroll
    for (int mi = 0; mi < 4; ++mi) {
      float a0 = fmaxf(acc[mi][2*g][0], acc[mi][2*g+1][0]);
      float a1 = fmaxf(acc[mi][2*g][1], acc[mi][2*g+1][1]);
      float a2 = fmaxf(acc[mi][2*g][2], acc[mi][2*g+1][2]);
      float a3 = fmaxf(acc[mi][2*g][3], acc[mi][2*g+1][3]);
      #pragma unroll
      for (int off = 1; off < 16; off <<= 1) {
        a0 = fmaxf(a0, __shfl_xor(a0, off));
        a1 = fmaxf(a1, __shfl_xor(a1, off));
        a2 = fmaxf(a2, __shfl_xor(a2, off));
        a3 = fmaxf(a3, __shfl_xor(a3, off));
      }
      if (l15 == 0) {
        const int o = oB + mi*16;
        outF[((size_t)bI*256 + o+0)*512 + mm] = a0;
        outF[((size_t)bI*256 + o+1)*512 + mm] = a1;
        outF[((size_t)bI*256 + o+2)*512 + mm] = a2;
        outF[((size_t)bI*256 + o+3)*512 + mm] = a3;
      }
    }
  }
}

extern "C" void kernel_launch(void* const* d_in, const int* in_sizes, int n_in,
                              void* d_out, int out_size, void* d_ws, size_t ws_size,
                              hipStream_t stream)
{
  (void)in_sizes; (void)n_in; (void)out_size; (void)ws_size;
  const float* p   = (const float*)d_in[0];
  const float* x   = (const float*)d_in[1];
  const float* W0  = (const float*)d_in[2];
  const float* g0  = (const float*)d_in[3];
  const float* be0 = (const float*)d_in[4];
  const float* W1  = (const float*)d_in[5];
  const float* b1  = (const float*)d_in[6];
  const float* W2  = (const float*)d_in[7];
  const float* g2  = (const float*)d_in[8];
  const float* be2 = (const float*)d_in[9];
  const float* W3  = (const float*)d_in[10];
  const float* b3  = (const float*)d_in[11];
  float* out  = (float*)d_out;
  float* outP = out;
  float* outC = out + 196608;
  float* outX = out + 208896;
  float* outF = out + 405504;
  char* ws = (char*)d_ws;
  u16* h2    = (u16*)(ws);                 // 67108864 B
  u16* h3    = (u16*)(ws + 67108864);      // 134217728 B
  u16* f0    = (u16*)(ws + 201326592);     // 1572864 B
  u16* fmaxb = (u16*)(ws + 202899456);     // 2097152 B
  float* fmb = (float*)(ws + 204996608);   // 8388608 B
  u16* w1b   = (u16*)(ws + 213385216);     // 131072 B
  u16* w2b   = (u16*)(ws + 213516288);     // 524288 B
  u16* w3b   = (u16*)(ws + 214040576);     // 262144 B
  int* idxb  = (int*)(ws + 214302720);     // 16384 B
  float* statz = (float*)(ws + 214319104); // 12288 B (zeroed each call by prep)
  float* cov  = statz;                 // 27 floats
  float* s0 = statz + 1536;   float* t0 = statz + 1792;
  float* s2 = statz + 2048;   float* t2 = statz + 2560;
  float* pS  = (float*)(ws + 214331392);   // 2097152 B  (4096 blocks x 128 ch)
  float* pQ  = (float*)(ws + 216428544);   // 2097152 B

  k_fps_prep<<<216, 512, 0, stream>>>(p, x, W1, W2, W3, outP, outC, outX,
                                      w1b, w2b, w3b, statz, idxb);
  k_group<<<1024, 256, 0, stream>>>(p, x, outC, idxb, f0);
  k_cov<<<512, 256, 0, stream>>>(f0, cov);
  k_fin1<<<1, 256, 0, stream>>>(cov, W0, g0, be0, s0, t0);
  k_gemm12<<<2048, 256, 0, stream>>>(w1b, f0, W0, s0, t0, b1, h2, fmaxb);
  k_fmb<<<128, 256, 0, stream>>>(w2b, fmaxb, fmb);
  k_gemm3<<<4096, 256, 0, stream>>>(w2b, h2, fmb, h3, pS, pQ);
  k_red<<<512, 256, 0, stream>>>(pS, pQ, g2, be2, s2, t2);
  k_gemm4<<<2048, 256, 0, stream>>>(w3b, h3, s2, t2, b3, outF);
}